// Round 11
// baseline (41.051 us; speedup 1.0000x reference)
//
#include <hip/hip_runtime.h>
#include <math.h>

#define NPTS   131072
#define MBOX   128
#define NBOX   256
#define NFPS   512

#define NTHR   1024
#define NWAVE  16
#define PPW    (NPTS / NWAVE)       // 8192 points per wave
#define NGRP   (PPW / 64)           // 128 ballot-groups per wave
#define DWPB   (NPTS / 32)          // 4096 bitmask dwords per box
#define RING   7                    // ring slots per wave (depth 6 in flight)
#define MAIN_ITERS (NGRP - 6)       // 122

typedef const __attribute__((address_space(1))) void g_void;
typedef __attribute__((address_space(3))) void l_void;

// One block = one box; points streamed via async global->LDS DMA ring
// (wave-private, counted vmcnt, no barriers in the stream loop).
__global__ __launch_bounds__(NTHR)
void roi_one(const float* __restrict__ points,   // (N,4): [b,x,y,z]
             const float* __restrict__ boxes,    // (B,M,7)
             int* __restrict__ out_idx,          // (NBOX, 512)
             int* __restrict__ out_num)          // (NBOX)
{
    const int box  = blockIdx.x;                 // 0..255
    const int tid  = threadIdx.x;
    const int lane = tid & 63;
    const int w    = tid >> 6;

    __shared__ float4   s_ring[NWAVE][RING][64]; // 112 KB
    __shared__ unsigned s_bits[DWPB];            // 16 KB
    __shared__ int      s_wsum[NWAVE];

    // box params PER-THREAD (wave-uniform, deterministic -> identical bits).
    // fp32/f64 ops verbatim from passing kernels; param loads drain under trig.
    const float* bx = boxes + box * 7;
    const float cx = bx[0], cy = bx[1], cz = bx[2];
    const float hx = __fmul_rn(__fadd_rn(bx[4], 2.0f), 0.5f);   // f(bdy)
    const float hy = __fmul_rn(__fadd_rn(bx[3], 2.0f), 0.5f);   // f(bdx)
    const float hz = __fmul_rn(__fadd_rn(bx[5], 2.0f), 0.5f);
    const float hp = -__fadd_rn(bx[6], 1.5707963705062866f);    // fl32(pi/2)
    const float c  = (float)cos((double)hp);
    const float s  = (float)sin((double)hp);
    const float bBf = (float)(box >> 7);         // batch as exact float 0/1

    const float4* p4 = (const float4*)points + w * PPW + lane;

    // prologue: 6 DMAs in flight (slots 0..5)
    #pragma unroll
    for (int g = 0; g < 6; ++g)
        __builtin_amdgcn_global_load_lds((g_void*)(p4 + g * 64),
                                         (l_void*)&s_ring[w][g][0], 16, 0, 0);

#define ROI_TEST(q, out) do {                                              \
        const float dx_ = __fsub_rn((q).y, cx);                            \
        const float dy_ = __fsub_rn((q).z, cy);                            \
        const float dz_ = __fsub_rn((q).w, cz);                            \
        const float lx_ = __fadd_rn(__fmul_rn(dx_, c), __fmul_rn(dy_, s)); \
        const float ly_ = __fadd_rn(__fmul_rn(-dx_, s), __fmul_rn(dy_, c)); \
        (out) = __ballot(((q).x == bBf) & (fabsf(lx_) <= hx) &             \
                         (fabsf(ly_) <= hy) & (fabsf(dz_) <= hz));         \
    } while (0)

    const float4* gsrc = p4 + 6 * 64;            // next group to DMA
    int rslot = 0, wslot = 6;

    #pragma unroll 1
    for (int i = 0; i < MAIN_ITERS; ++i) {
        // oldest DMA (group i) retired when <=5 outstanding (in-order retire)
        asm volatile("s_waitcnt vmcnt(5)" ::: "memory");
        __builtin_amdgcn_sched_barrier(0);

        const float4 q = s_ring[w][rslot][lane];
        unsigned long long bal;
        ROI_TEST(q, bal);
        if (lane == 0)
            *(unsigned long long*)&s_bits[w * (NGRP * 2) + i * 2] = bal;

        // refill: group i+6 -> slot (i+6)%7 (never the slot read this iter)
        __builtin_amdgcn_global_load_lds((g_void*)gsrc,
                                         (l_void*)&s_ring[w][wslot][0], 16, 0, 0);
        gsrc += 64;
        rslot = (rslot == RING - 1) ? 0 : rslot + 1;
        wslot = (wslot == RING - 1) ? 0 : wslot + 1;
    }

    // drain and finish the last 6 groups
    asm volatile("s_waitcnt vmcnt(0)" ::: "memory");
    __builtin_amdgcn_sched_barrier(0);
    #pragma unroll 1
    for (int i = MAIN_ITERS; i < NGRP; ++i) {
        const float4 q = s_ring[w][rslot][lane];
        unsigned long long bal;
        ROI_TEST(q, bal);
        if (lane == 0)
            *(unsigned long long*)&s_bits[w * (NGRP * 2) + i * 2] = bal;
        rslot = (rslot == RING - 1) ? 0 : rslot + 1;
    }
    __syncthreads();

    // ---- ordered compaction (verbatim from passing R9 kernel) ----
    const uint4 qv = ((const uint4*)s_bits)[tid];     // conflict-free b128
    unsigned v[4] = {qv.x, qv.y, qv.z, qv.w};
    int cnt = __popc(v[0]) + __popc(v[1]) + __popc(v[2]) + __popc(v[3]);

    int incl = cnt;
    #pragma unroll
    for (int off = 1; off < 64; off <<= 1) {
        const int x = __shfl_up(incl, off, 64);
        if (lane >= off) incl += x;
    }
    if (lane == 63) s_wsum[w] = incl;
    __syncthreads();

    int wpre = 0, total = 0;
    #pragma unroll
    for (int ww = 0; ww < NWAVE; ++ww) {
        const int x = s_wsum[ww];
        if (ww < w) wpre += x;
        total += x;
    }
    int pos = wpre + (incl - cnt);
    const int pn = total < NFPS ? total : NFPS;

    const int obase = box * NFPS;
    if (tid < NFPS && tid >= pn) out_idx[obase + tid] = 0;   // zero tail

    const int pt0 = tid * 128;
    #pragma unroll
    for (int i = 0; i < 4; ++i) {
        unsigned x = v[i];
        while (x) {
            const int bpos = __ffs(x) - 1;
            if (pos < NFPS) out_idx[obase + pos] = pt0 + i * 32 + bpos;
            ++pos;
            x &= x - 1;
        }
    }
    if (tid == 0) out_num[box] = pn;
}

extern "C" void kernel_launch(void* const* d_in, const int* in_sizes, int n_in,
                              void* d_out, int out_size, void* d_ws, size_t ws_size,
                              hipStream_t stream) {
    const float* points = (const float*)d_in[0];   // (N,4) f32
    const float* boxes  = (const float*)d_in[1];   // (B,M,7) f32
    int* out_idx = (int*)d_out;                    // (B,M,512)
    int* out_num = (int*)d_out + NBOX * NFPS;      // (B,M)

    roi_one<<<NBOX, NTHR, 0, stream>>>(points, boxes, out_idx, out_num);
}

// Round 12
// 27.409 us; speedup vs baseline: 1.4977x; 1.4977x over previous
//
#include <hip/hip_runtime.h>
#include <math.h>

#define NPTS   131072
#define NBOX   256
#define NFPS   512

#define NTHR   1024
#define NWAVE  16
#define PPW    (NPTS / NWAVE)       // 8192 points per wave
#define ITERS  (PPW / 512)          // 16 (512 pts per wave-iter, 8 per lane)
#define DWPB   (NPTS / 32)          // 4096 bitmask dwords per box

#define GRIDC  64
#define XMIN   (-75.2f)
#define INVCELL (64.0f / 150.4f)

// ---- node 1: per-point u16 cell id (clamped binning, proven in R6) ----
__global__ __launch_bounds__(256)
void cellid_kernel(const float* __restrict__ points,       // (N,4)
                   unsigned short* __restrict__ cid)       // (N)
{
    const int i = blockIdx.x * 256 + threadIdx.x;
    const float4 p = ((const float4*)points)[i];
    const int b  = (int)p.x;                               // exact 0/1
    const int ix = min(GRIDC - 1, max(0, (int)floorf((p.y - XMIN) * INVCELL)));
    const int iy = min(GRIDC - 1, max(0, (int)floorf((p.z - XMIN) * INVCELL)));
    cid[i] = (unsigned short)(b * 4096 + iy * 64 + ix);
}

// ---- node 2: one block per box; stream cids, exact-test only candidates ----
__global__ __launch_bounds__(NTHR)
void roi_box(const float* __restrict__ points,             // (N,4)
             const unsigned short* __restrict__ cid,       // (N)
             const float* __restrict__ boxes,              // (B,M,7)
             int* __restrict__ out_idx,                    // (NBOX, 512)
             int* __restrict__ out_num)                    // (NBOX)
{
    const int box  = blockIdx.x;
    const int tid  = threadIdx.x;
    const int lane = tid & 63;
    const int w    = tid >> 6;

    __shared__ unsigned s_bits[DWPB];            // 16 KB
    __shared__ int      s_wsum[NWAVE];

    ((uint4*)s_bits)[tid] = make_uint4(0u, 0u, 0u, 0u);    // zero bitmask

    // box params PER-THREAD (wave-uniform, deterministic -> identical bits).
    // fp32/f64 ops verbatim from passing kernels (bit-exact decisions).
    const float* bx = boxes + box * 7;
    const float cx = bx[0], cy = bx[1], cz = bx[2];
    const float hx = __fmul_rn(__fadd_rn(bx[4], 2.0f), 0.5f);   // f(bdy)
    const float hy = __fmul_rn(__fadd_rn(bx[3], 2.0f), 0.5f);   // f(bdx)
    const float hz = __fmul_rn(__fadd_rn(bx[5], 2.0f), 0.5f);
    const float hp = -__fadd_rn(bx[6], 1.5707963705062866f);    // fl32(pi/2)
    const float c  = (float)cos((double)hp);
    const float s  = (float)sin((double)hp);
    const int   b  = box >> 7;

    // conservative AABB cell range (verbatim from R6, refcheck-proven)
    const float R = sqrtf(hx * hx + hy * hy) + 0.1f;
    const int ix0 = max(0, (int)floorf((cx - R - XMIN) * INVCELL));
    const int ix1 = min(GRIDC - 1, (int)floorf((cx + R - XMIN) * INVCELL));
    const int iy0 = max(0, (int)floorf((cy - R - XMIN) * INVCELL));
    const int iy1 = min(GRIDC - 1, (int)floorf((cy + R - XMIN) * INVCELL));
    const int lo = b * 4096 + iy0 * 64 + ix0;
    const int hi = b * 4096 + iy1 * 64 + ix1;
    __syncthreads();

#define ROI_EXACT(idx) do {                                                \
        const float4 q = ((const float4*)points)[idx];                     \
        const float dx_ = __fsub_rn(q.y, cx);                              \
        const float dy_ = __fsub_rn(q.z, cy);                              \
        const float dz_ = __fsub_rn(q.w, cz);                              \
        const float lx_ = __fadd_rn(__fmul_rn(dx_, c), __fmul_rn(dy_, s)); \
        const float ly_ = __fadd_rn(__fmul_rn(-dx_, s), __fmul_rn(dy_, c)); \
        if ((fabsf(lx_) <= hx) & (fabsf(ly_) <= hy) & (fabsf(dz_) <= hz))  \
            atomicOr(&s_bits[(idx) >> 5], 1u << ((idx) & 31));             \
    } while (0)

    // stream this wave's 8192 cids as uint4 (8 pts/lane/iter), 2-stage pipeline
    const uint4* c4 = (const uint4*)(cid + w * PPW) + lane;
    uint4 cur = c4[0];
    #pragma unroll 1
    for (int it = 0; it < ITERS; ++it) {
        uint4 nxt = cur;
        if (it + 1 < ITERS) nxt = c4[(it + 1) * 64];
        const int pbase = w * PPW + it * 512 + lane * 8;
        const unsigned wds[4] = {cur.x, cur.y, cur.z, cur.w};
        #pragma unroll
        for (int u = 0; u < 4; ++u) {
            const int cA = (int)(wds[u] & 0xffffu);
            const int cB = (int)(wds[u] >> 16);
            if (cA >= lo && cA <= hi && (cA & 63) >= ix0 && (cA & 63) <= ix1)
                ROI_EXACT(pbase + 2 * u);
            if (cB >= lo && cB <= hi && (cB & 63) >= ix0 && (cB & 63) <= ix1)
                ROI_EXACT(pbase + 2 * u + 1);
        }
        cur = nxt;
    }
    __syncthreads();

    // ---- ordered compaction (verbatim from passing R9 kernel) ----
    const uint4 qv = ((const uint4*)s_bits)[tid];     // conflict-free b128
    unsigned v[4] = {qv.x, qv.y, qv.z, qv.w};
    int cnt = __popc(v[0]) + __popc(v[1]) + __popc(v[2]) + __popc(v[3]);

    int incl = cnt;
    #pragma unroll
    for (int off = 1; off < 64; off <<= 1) {
        const int x = __shfl_up(incl, off, 64);
        if (lane >= off) incl += x;
    }
    if (lane == 63) s_wsum[w] = incl;
    __syncthreads();

    int wpre = 0, total = 0;
    #pragma unroll
    for (int ww = 0; ww < NWAVE; ++ww) {
        const int x = s_wsum[ww];
        if (ww < w) wpre += x;
        total += x;
    }
    int pos = wpre + (incl - cnt);
    const int pn = total < NFPS ? total : NFPS;

    const int obase = box * NFPS;
    if (tid < NFPS && tid >= pn) out_idx[obase + tid] = 0;   // zero tail

    const int pt0 = tid * 128;
    #pragma unroll
    for (int i = 0; i < 4; ++i) {
        unsigned x = v[i];
        while (x) {
            const int bpos = __ffs(x) - 1;
            if (pos < NFPS) out_idx[obase + pos] = pt0 + i * 32 + bpos;
            ++pos;
            x &= x - 1;
        }
    }
    if (tid == 0) out_num[box] = pn;
}

extern "C" void kernel_launch(void* const* d_in, const int* in_sizes, int n_in,
                              void* d_out, int out_size, void* d_ws, size_t ws_size,
                              hipStream_t stream) {
    const float* points = (const float*)d_in[0];   // (N,4) f32
    const float* boxes  = (const float*)d_in[1];   // (B,M,7) f32
    int* out_idx = (int*)d_out;                    // (B,M,512)
    int* out_num = (int*)d_out + NBOX * NFPS;      // (B,M)
    unsigned short* cid = (unsigned short*)d_ws;   // 256 KB

    cellid_kernel<<<NPTS / 256, 256, 0, stream>>>(points, cid);
    roi_box<<<NBOX, NTHR, 0, stream>>>(points, cid, boxes, out_idx, out_num);
}